// Round 4
// baseline (857.923 us; speedup 1.0000x reference)
//
#include <hip/hip_runtime.h>

#define D_DIM 128
#define EDGE_DIM 32
#define BN_EPS 1e-5f
#define CHUNK 128

typedef __attribute__((ext_vector_type(8))) _Float16 f16x8;
typedef __attribute__((ext_vector_type(4))) float f32x4;
typedef unsigned short ushort_t;

__device__ __forceinline__ unsigned short f2h(float f) {
    union { _Float16 h; unsigned short u; } c;
    c.h = (_Float16)f;
    return c.u;
}
__device__ __forceinline__ unsigned pk2h(float lo, float hi) {
    return (unsigned)f2h(lo) | ((unsigned)f2h(hi) << 16);
}
__device__ __forceinline__ float h2f(unsigned short u) {
    union { unsigned short u; _Float16 h; } c;
    c.u = u;
    return (float)c.h;
}

// ---------------------------------------------------------------------------
// CSR build: histogram -> single-block scan -> scatter
// ---------------------------------------------------------------------------
__global__ __launch_bounds__(256) void hist_kernel(
    const int* __restrict__ dst, int* __restrict__ cnt, int E)
{
    for (int e = blockIdx.x * 256 + threadIdx.x; e < E; e += gridDim.x * 256)
        atomicAdd(&cnt[dst[e]], 1);
}

__global__ __launch_bounds__(1024) void scan_kernel(
    const int* __restrict__ cnt, int* __restrict__ off,
    int* __restrict__ cur, int n, int chunk)
{
    __shared__ int part[1024];
    const int t = threadIdx.x;
    const int b = t * chunk;
    const int e = min(b + chunk, n);
    int s = 0;
    for (int i = b; i < e; ++i) s += cnt[i];
    part[t] = s;
    __syncthreads();
    for (int d = 1; d < 1024; d <<= 1) {
        const int v = (t >= d) ? part[t - d] : 0;
        __syncthreads();
        part[t] += v;
        __syncthreads();
    }
    int run = (t > 0) ? part[t - 1] : 0;
    for (int i = b; i < e; ++i) {
        off[i] = run;
        cur[i] = run;
        run += cnt[i];
    }
    if (t == 1023) off[n] = run;
}

__global__ __launch_bounds__(256) void scatter_kernel(
    const int* __restrict__ src, const int* __restrict__ dst,
    int* __restrict__ cur, int2* __restrict__ csr_se,
    int* __restrict__ csr_eid, int E)
{
    for (int e = blockIdx.x * 256 + threadIdx.x; e < E; e += gridDim.x * 256) {
        const int d = dst[e];
        const int p = atomicAdd(&cur[d], 1);
        csr_se[p] = make_int2(src[e], d);
        csr_eid[p] = e;
    }
}

// ---------------------------------------------------------------------------
// Permute edge_attr into CSR order, fp16, in MFMA A-fragment-linear layout:
// byte offset(p, q) = (p>>7)*8192 + ((p>>4)&7)*1024 + q*256 + (p&15)*16
// (q = k-octet 0..3; 8 halfs of k = q*8..q*8+7)
// ---------------------------------------------------------------------------
__global__ __launch_bounds__(256) void ea_permute_kernel(
    const float* __restrict__ ea, const int* __restrict__ csr_eid,
    ushort_t* __restrict__ ea_frag, int E)
{
    const int idx = blockIdx.x * 256 + threadIdx.x;
    const int p = idx >> 2;
    if (p >= E) return;
    const int q = idx & 3;
    const int eid = csr_eid[p];
    const float4 a = *(const float4*)(ea + (size_t)eid * EDGE_DIM + q * 8);
    const float4 b = *(const float4*)(ea + (size_t)eid * EDGE_DIM + q * 8 + 4);
    uint4 o;
    o.x = pk2h(a.x, a.y); o.y = pk2h(a.z, a.w);
    o.z = pk2h(b.x, b.y); o.w = pk2h(b.z, b.w);
    const size_t off = ((size_t)(p >> 7)) * 8192 + (size_t)(((p >> 4) & 7)) * 1024
                     + (size_t)q * 256 + (size_t)(p & 15) * 16;
    *(uint4*)((char*)ea_frag + off) = o;
}

// ---------------------------------------------------------------------------
// Per-layer W_lin -> fp16 B-fragment-linear (8 KB): slot s = cb*64+ko*16+c15
// holds 8 halfs W[ko*8+j][cb*16+c15], at byte offset s*16.
// ---------------------------------------------------------------------------
__global__ __launch_bounds__(256) void wfrag_build_kernel(
    const float* __restrict__ Wl, ushort_t* __restrict__ wfrag)
{
#pragma unroll
    for (int r = 0; r < 2; ++r) {
        const int s = threadIdx.x * 2 + r;
        const int cb = s >> 6, ko = (s >> 4) & 3, c15 = s & 15;
        const int col = cb * 16 + c15;
        float v[8];
#pragma unroll
        for (int j = 0; j < 8; ++j) v[j] = Wl[(ko * 8 + j) * D_DIM + col];
        uint4 o;
        o.x = pk2h(v[0], v[1]); o.y = pk2h(v[2], v[3]);
        o.z = pk2h(v[4], v[5]); o.w = pk2h(v[6], v[7]);
        *(uint4*)((char*)wfrag + (size_t)s * 16) = o;
    }
}

// ---------------------------------------------------------------------------
// Fused edge pass: per 128-edge chunk,
//   phase 1: e = ea_csr @ W_lin via MFMA  -> LDS (fp16, col-major)
//   phase 2: segmented reduce agg[dst] += relu(x'[src] + e + b_lin)
// x' = relu(x*sc+sh) for layers >= 1 (previous BN folded in).
// ---------------------------------------------------------------------------
template<int XFORM>
__global__ __launch_bounds__(256) void fused_edge_kernel(
    const float* __restrict__ x,
    const int2*  __restrict__ csr_se,
    const ushort_t* __restrict__ ea_frag,
    const ushort_t* __restrict__ wfrag,
    const float* __restrict__ bl,
    const float* __restrict__ scsh,
    float*       __restrict__ agg,
    int E)
{
    __shared__ ushort_t eT[128 * 132];   // eT[col*132 + row], stride 264 B
    const int tid  = threadIdx.x;
    const int lane = tid & 63;
    const int w    = tid >> 6;
    const int fr   = lane & 15;
    const int fg   = lane >> 4;

    // --- phase 1: MFMA e-tile ---
    f16x8 bfr[8];
#pragma unroll
    for (int cb = 0; cb < 8; ++cb)
        bfr[cb] = *(const f16x8*)(wfrag + cb * 512 + fg * 128 + fr * 8);

#pragma unroll
    for (int rr = 0; rr < 2; ++rr) {
        const int rb = w * 2 + rr;
        const f16x8 af = *(const f16x8*)(ea_frag
            + (size_t)blockIdx.x * 4096 + rb * 512 + fg * 128 + fr * 8);
        f32x4 acc[8];
#pragma unroll
        for (int cb = 0; cb < 8; ++cb) {
            const f32x4 z = {0.f, 0.f, 0.f, 0.f};
            acc[cb] = __builtin_amdgcn_mfma_f32_16x16x32_f16(af, bfr[cb], z, 0, 0, 0);
        }
#pragma unroll
        for (int cb = 0; cb < 8; ++cb) {
            const int col = cb * 16 + fr;
            const int row = rb * 16 + fg * 4;
            ushort4 o;
            o.x = f2h(acc[cb][0]); o.y = f2h(acc[cb][1]);
            o.z = f2h(acc[cb][2]); o.w = f2h(acc[cb][3]);
            *(ushort4*)&eT[col * 132 + row] = o;
        }
    }
    __syncthreads();

    // --- phase 2: segmented reduce over 32 CSR positions per wave ---
    const float b0 = bl[lane];
    const float b1 = bl[64 + lane];
    float sc0 = 1.f, sh0 = 0.f, sc1 = 1.f, sh1 = 0.f;
    if (XFORM) {
        sc0 = scsh[lane];      sh0 = scsh[128 + lane];
        sc1 = scsh[64 + lane]; sh1 = scsh[192 + lane];
    }

    const int p0 = blockIdx.x * CHUNK + w * 32;
    float a0 = 0.f, a1 = 0.f;
    int dcur = -1;
    bool pending = false;
#pragma unroll 1
    for (int i = 0; i < 32; ++i) {
        const int p = p0 + i;
        if (p >= E) break;
        const int2 se = csr_se[p];
        const int s = __builtin_amdgcn_readfirstlane(se.x);
        const int d = __builtin_amdgcn_readfirstlane(se.y);
        int dn = -1;
        if (p + 1 < E) dn = __builtin_amdgcn_readfirstlane(csr_se[p + 1].y);
        const float* __restrict__ xr = x + (size_t)s * D_DIM;
        float x0 = xr[lane], x1 = xr[64 + lane];
        if (XFORM) {
            x0 = fmaxf(fmaf(x0, sc0, sh0), 0.f);
            x1 = fmaxf(fmaf(x1, sc1, sh1), 0.f);
        }
        const float e0 = h2f(eT[lane * 132 + (w * 32 + i)]);
        const float e1 = h2f(eT[(64 + lane) * 132 + (w * 32 + i)]);
        a0 += fmaxf(x0 + e0 + b0, 0.f);
        a1 += fmaxf(x1 + e1 + b1, 0.f);
        dcur = d;
        pending = true;
        if (d != dn) {
            unsafeAtomicAdd(&agg[(size_t)d * D_DIM + lane],      a0);
            unsafeAtomicAdd(&agg[(size_t)d * D_DIM + 64 + lane], a1);
            a0 = 0.f; a1 = 0.f;
            pending = false;
        }
    }
    if (pending) {
        unsafeAtomicAdd(&agg[(size_t)dcur * D_DIM + lane],      a0);
        unsafeAtomicAdd(&agg[(size_t)dcur * D_DIM + 64 + lane], a1);
    }
}

// ---------------------------------------------------------------------------
// MFMA GEMM 1: h1 = relu( (xform(x) + agg) @ W1 + b1 )  -> fp16 output
// ---------------------------------------------------------------------------
template<int XFORM>
__global__ __launch_bounds__(256) void gemm1_kernel(
    const float* __restrict__ A,
    const float* __restrict__ agg,
    const float* __restrict__ W,
    const float* __restrict__ bias,
    const float* __restrict__ scsh,
    ushort_t* __restrict__ h1,
    int M)
{
    __shared__ char ATb[128 * 256];
    __shared__ char WTb[128 * 256];
    const int tid = threadIdx.x;
    const int m0  = blockIdx.x * 128;

#pragma unroll
    for (int i = 0; i < 16; ++i) {
        const int idx = i * 256 + tid;
        const int r = idx >> 5, c4 = idx & 31;
        const int row = m0 + r;
        f32x4 v = {0.f, 0.f, 0.f, 0.f};
        if (row < M) {
            v = *(const f32x4*)(A + (size_t)row * 128 + c4 * 4);
            if (XFORM) {
                const f32x4 s4 = *(const f32x4*)(scsh + c4 * 4);
                const f32x4 h4 = *(const f32x4*)(scsh + 128 + c4 * 4);
#pragma unroll
                for (int j = 0; j < 4; ++j)
                    v[j] = fmaxf(fmaf(v[j], s4[j], h4[j]), 0.f);
            }
            const f32x4 g = *(const f32x4*)(agg + (size_t)row * 128 + c4 * 4);
            v += g;
        }
        uint2 p; p.x = pk2h(v[0], v[1]); p.y = pk2h(v[2], v[3]);
        *(uint2*)(ATb + r * 256 + ((c4 * 8) ^ ((r & 7) << 4))) = p;
    }
#pragma unroll
    for (int i = 0; i < 8; ++i) {
        const int c4 = (tid >> 6) + 4 * i;
        const int kp = tid & 63;
        const f32x4 wa = *(const f32x4*)(W + (size_t)(2 * kp) * 128 + c4 * 4);
        const f32x4 wb = *(const f32x4*)(W + (size_t)(2 * kp + 1) * 128 + c4 * 4);
#pragma unroll
        for (int j = 0; j < 4; ++j) {
            const int col = c4 * 4 + j;
            *(unsigned*)(WTb + col * 256 + ((kp * 4) ^ ((col & 7) << 4))) = pk2h(wa[j], wb[j]);
        }
    }
    __syncthreads();

    const int lane = tid & 63;
    const int w    = tid >> 6;
    const int fr   = lane & 15;
    const int fg   = lane >> 4;

    f32x4 acc[2][8];
#pragma unroll
    for (int a = 0; a < 2; ++a)
#pragma unroll
        for (int b = 0; b < 8; ++b) acc[a][b] = (f32x4){0.f, 0.f, 0.f, 0.f};

    const int ar0 = w * 32 + fr;
    const int asz = (ar0 & 7) << 4;
#pragma unroll
    for (int ks = 0; ks < 4; ++ks) {
        const int kb = ks * 64 + fg * 16;
        const f16x8 a0 = *(const f16x8*)(ATb + ar0 * 256 + (kb ^ asz));
        const f16x8 a1 = *(const f16x8*)(ATb + (ar0 + 16) * 256 + (kb ^ asz));
#pragma unroll
        for (int cb = 0; cb < 8; ++cb) {
            const int col = cb * 16 + fr;
            const f16x8 b = *(const f16x8*)(WTb + col * 256 + (kb ^ ((col & 7) << 4)));
            acc[0][cb] = __builtin_amdgcn_mfma_f32_16x16x32_f16(a0, b, acc[0][cb], 0, 0, 0);
            acc[1][cb] = __builtin_amdgcn_mfma_f32_16x16x32_f16(a1, b, acc[1][cb], 0, 0, 0);
        }
    }

    float bv[8];
#pragma unroll
    for (int cb = 0; cb < 8; ++cb) bv[cb] = bias[cb * 16 + fr];
#pragma unroll
    for (int rf = 0; rf < 2; ++rf) {
        const int r0 = m0 + w * 32 + rf * 16 + fg * 4;
#pragma unroll
        for (int cb = 0; cb < 8; ++cb) {
            const int col = cb * 16 + fr;
#pragma unroll
            for (int j = 0; j < 4; ++j) {
                const int row = r0 + j;
                if (row < M) {
                    const float v = fmaxf(acc[rf][cb][j] + bv[cb], 0.f);
                    h1[(size_t)row * 128 + col] = f2h(v);
                }
            }
        }
    }
}

// ---------------------------------------------------------------------------
// MFMA GEMM 2: h = h1 @ W2 + b2 (fp32 out) + fused BN column sums/sumsq.
// ---------------------------------------------------------------------------
__global__ __launch_bounds__(256) void gemm2_kernel(
    const ushort_t* __restrict__ h1,
    const float* __restrict__ W,
    const float* __restrict__ bias,
    float* __restrict__ C,
    float* __restrict__ sums,
    int M)
{
    __shared__ char ATb[128 * 256];
    __shared__ char WTb[128 * 256];
    __shared__ float bsum[256];
    const int tid = threadIdx.x;
    const int m0  = blockIdx.x * 128;

    bsum[tid] = 0.f;

#pragma unroll
    for (int i = 0; i < 8; ++i) {
        const int idx = i * 256 + tid;
        const int r = idx >> 4, c8 = idx & 15;
        const int row = m0 + r;
        uint4 v = make_uint4(0u, 0u, 0u, 0u);
        if (row < M) v = *(const uint4*)(h1 + (size_t)row * 128 + c8 * 8);
        *(uint4*)(ATb + r * 256 + ((c8 * 16) ^ ((r & 7) << 4))) = v;
    }
#pragma unroll
    for (int i = 0; i < 8; ++i) {
        const int c4 = (tid >> 6) + 4 * i;
        const int kp = tid & 63;
        const f32x4 wa = *(const f32x4*)(W + (size_t)(2 * kp) * 128 + c4 * 4);
        const f32x4 wb = *(const f32x4*)(W + (size_t)(2 * kp + 1) * 128 + c4 * 4);
#pragma unroll
        for (int j = 0; j < 4; ++j) {
            const int col = c4 * 4 + j;
            *(unsigned*)(WTb + col * 256 + ((kp * 4) ^ ((col & 7) << 4))) = pk2h(wa[j], wb[j]);
        }
    }
    __syncthreads();

    const int lane = tid & 63;
    const int w    = tid >> 6;
    const int fr   = lane & 15;
    const int fg   = lane >> 4;

    f32x4 acc[2][8];
#pragma unroll
    for (int a = 0; a < 2; ++a)
#pragma unroll
        for (int b = 0; b < 8; ++b) acc[a][b] = (f32x4){0.f, 0.f, 0.f, 0.f};

    const int ar0 = w * 32 + fr;
    const int asz = (ar0 & 7) << 4;
#pragma unroll
    for (int ks = 0; ks < 4; ++ks) {
        const int kb = ks * 64 + fg * 16;
        const f16x8 a0 = *(const f16x8*)(ATb + ar0 * 256 + (kb ^ asz));
        const f16x8 a1 = *(const f16x8*)(ATb + (ar0 + 16) * 256 + (kb ^ asz));
#pragma unroll
        for (int cb = 0; cb < 8; ++cb) {
            const int col = cb * 16 + fr;
            const f16x8 b = *(const f16x8*)(WTb + col * 256 + (kb ^ ((col & 7) << 4)));
            acc[0][cb] = __builtin_amdgcn_mfma_f32_16x16x32_f16(a0, b, acc[0][cb], 0, 0, 0);
            acc[1][cb] = __builtin_amdgcn_mfma_f32_16x16x32_f16(a1, b, acc[1][cb], 0, 0, 0);
        }
    }

    float bv[8];
#pragma unroll
    for (int cb = 0; cb < 8; ++cb) bv[cb] = bias[cb * 16 + fr];
    float s[8], q[8];
#pragma unroll
    for (int cb = 0; cb < 8; ++cb) { s[cb] = 0.f; q[cb] = 0.f; }

#pragma unroll
    for (int rf = 0; rf < 2; ++rf) {
        const int r0 = m0 + w * 32 + rf * 16 + fg * 4;
#pragma unroll
        for (int cb = 0; cb < 8; ++cb) {
            const int col = cb * 16 + fr;
#pragma unroll
            for (int j = 0; j < 4; ++j) {
                const int row = r0 + j;
                if (row < M) {
                    const float v = acc[rf][cb][j] + bv[cb];
                    C[(size_t)row * 128 + col] = v;
                    s[cb] += v;
                    q[cb] += v * v;
                }
            }
        }
    }
#pragma unroll
    for (int cb = 0; cb < 8; ++cb) {
        float ss = s[cb]; ss += __shfl_down(ss, 32); ss += __shfl_down(ss, 16);
        float qq = q[cb]; qq += __shfl_down(qq, 32); qq += __shfl_down(qq, 16);
        if (lane < 16) {
            atomicAdd(&bsum[cb * 16 + lane], ss);
            atomicAdd(&bsum[128 + cb * 16 + lane], qq);
        }
    }
    __syncthreads();
    unsafeAtomicAdd(&sums[tid], bsum[tid]);
}

// ---------------------------------------------------------------------------
__global__ __launch_bounds__(128) void bn_finalize_kernel(
    const float* __restrict__ sums,
    const float* __restrict__ gamma, const float* __restrict__ beta,
    float* __restrict__ scsh, float invM)
{
    const int c = threadIdx.x;
    const float mu  = sums[c] * invM;
    const float var = sums[128 + c] * invM - mu * mu;
    const float sc  = gamma[c] * rsqrtf(var + BN_EPS);
    scsh[c]       = sc;
    scsh[128 + c] = beta[c] - mu * sc;
}

__global__ __launch_bounds__(256) void bn_apply_final(
    float* __restrict__ h, const float* __restrict__ scsh, int M)
{
    __shared__ float sc[128], sh[128];
    if (threadIdx.x < 128) {
        sc[threadIdx.x] = scsh[threadIdx.x];
        sh[threadIdx.x] = scsh[128 + threadIdx.x];
    }
    __syncthreads();
    const size_t total = (size_t)M * D_DIM / 4;
    for (size_t i = (size_t)blockIdx.x * 256 + threadIdx.x; i < total;
         i += (size_t)gridDim.x * 256) {
        float4 v = ((const float4*)h)[i];
        const int cb = ((int)(i & 31)) * 4;
        v.x = fmaxf(fmaf(v.x, sc[cb + 0], sh[cb + 0]), 0.f);
        v.y = fmaxf(fmaf(v.y, sc[cb + 1], sh[cb + 1]), 0.f);
        v.z = fmaxf(fmaf(v.z, sc[cb + 2], sh[cb + 2]), 0.f);
        v.w = fmaxf(fmaf(v.w, sc[cb + 3], sh[cb + 3]), 0.f);
        ((float4*)h)[i] = v;
    }
}

// ---------------------------------------------------------------------------
extern "C" void kernel_launch(void* const* d_in, const int* in_sizes, int n_in,
                              void* d_out, int out_size, void* d_ws, size_t ws_size,
                              hipStream_t stream)
{
    const float* x_in  = (const float*)d_in[0];
    const int*   ei    = (const int*)  d_in[1];
    const float* ea    = (const float*)d_in[2];
    const float* W_lin = (const float*)d_in[3];
    const float* b_lin = (const float*)d_in[4];
    const float* W1    = (const float*)d_in[5];
    const float* b1    = (const float*)d_in[6];
    const float* W2    = (const float*)d_in[7];
    const float* b2    = (const float*)d_in[8];
    const float* gamma = (const float*)d_in[9];
    const float* beta  = (const float*)d_in[10];

    const int N = in_sizes[0] / D_DIM;              // 50000
    const int E = in_sizes[2] / EDGE_DIM;           // 600000
    const int L = in_sizes[3] / (EDGE_DIM * D_DIM); // 3
    const int NC = (E + CHUNK - 1) / CHUNK;         // edge chunks

    const int* src = ei;
    const int* dst = ei + E;

    float* out = (float*)d_out;

    // ---- ws layout (16B-aligned regions) ----
    char* wp = (char*)d_ws;
    auto take = [&wp](size_t bytes) {
        char* r = wp;
        wp += (bytes + 15) & ~(size_t)15;
        return r;
    };
    float*     agg     = (float*)    take((size_t)N * D_DIM * 4);
    ushort_t*  h1      = (ushort_t*) take((size_t)N * D_DIM * 2);
    float*     sums    = (float*)    take(256 * 4);
    float*     scsh    = (float*)    take(256 * 4);
    ushort_t*  wfrag   = (ushort_t*) take(8192);
    int*       cnt     = (int*)      take((size_t)N * 4);
    int*       row_off = (int*)      take((size_t)(N + 1) * 4);
    int*       cur     = (int*)      take((size_t)N * 4);
    int2*      csr_se  = (int2*)     take((size_t)E * 8);
    int*       csr_eid = (int*)      take((size_t)E * 4);
    ushort_t*  ea_frag = (ushort_t*) take((size_t)NC * 8192);

    const int gemmBlocks = (N + 127) / 128;

    // ---- CSR build + edge_attr fragment permute (once per call) ----
    hipMemsetAsync(cnt, 0, (size_t)N * sizeof(int), stream);
    hist_kernel<<<1024, 256, 0, stream>>>(dst, cnt, E);
    scan_kernel<<<1, 1024, 0, stream>>>(cnt, row_off, cur, N, (N + 1023) / 1024);
    scatter_kernel<<<1024, 256, 0, stream>>>(src, dst, cur, csr_se, csr_eid, E);
    ea_permute_kernel<<<(E * 4 + 255) / 256, 256, 0, stream>>>(ea, csr_eid, ea_frag, E);

    for (int l = 0; l < L; ++l) {
        const float* xin = (l == 0) ? x_in : out;
        hipMemsetAsync(sums, 0, 256 * sizeof(float), stream);
        hipMemsetAsync(agg, 0, (size_t)N * D_DIM * sizeof(float), stream);

        const float* Wl_l = W_lin + (size_t)l * EDGE_DIM * D_DIM;
        const float* bl_l = b_lin + (size_t)l * D_DIM;
        const float* W1_l = W1 + (size_t)l * D_DIM * D_DIM;
        const float* b1_l = b1 + (size_t)l * D_DIM;
        const float* W2_l = W2 + (size_t)l * D_DIM * D_DIM;
        const float* b2_l = b2 + (size_t)l * D_DIM;

        wfrag_build_kernel<<<1, 256, 0, stream>>>(Wl_l, wfrag);

        if (l == 0) {
            fused_edge_kernel<0><<<NC, 256, 0, stream>>>(
                xin, csr_se, ea_frag, wfrag, bl_l, nullptr, agg, E);
            gemm1_kernel<0><<<gemmBlocks, 256, 0, stream>>>(
                xin, agg, W1_l, b1_l, nullptr, h1, N);
        } else {
            fused_edge_kernel<1><<<NC, 256, 0, stream>>>(
                xin, csr_se, ea_frag, wfrag, bl_l, scsh, agg, E);
            gemm1_kernel<1><<<gemmBlocks, 256, 0, stream>>>(
                xin, agg, W1_l, b1_l, scsh, h1, N);
        }

        gemm2_kernel<<<gemmBlocks, 256, 0, stream>>>(
            h1, W2_l, b2_l, out, sums, N);

        bn_finalize_kernel<<<1, 128, 0, stream>>>(
            sums, gamma + (size_t)l * D_DIM, beta + (size_t)l * D_DIM,
            scsh, 1.f / (float)N);
    }

    bn_apply_final<<<2048, 256, 0, stream>>>(out, scsh, N);
}

// Round 5
// 580.735 us; speedup vs baseline: 1.4773x; 1.4773x over previous
//
#include <hip/hip_runtime.h>

#define D_DIM 128
#define EDGE_DIM 32
#define BN_EPS 1e-5f

typedef __attribute__((ext_vector_type(8))) _Float16 f16x8;
typedef __attribute__((ext_vector_type(2))) _Float16 half2v;
typedef __attribute__((ext_vector_type(4))) float f32x4;
typedef unsigned short ushort_t;

__device__ __forceinline__ unsigned short f2h(float f) {
    union { _Float16 h; unsigned short u; } c;
    c.h = (_Float16)f;
    return c.u;
}
__device__ __forceinline__ unsigned pk2h(float lo, float hi) {
    return (unsigned)f2h(lo) | ((unsigned)f2h(hi) << 16);
}
__device__ __forceinline__ half2v asH2(unsigned u) {
    union { unsigned u; half2v h; } c;
    c.u = u;
    return c.h;
}
__device__ __forceinline__ float fdot2f(half2v a, half2v b, float c) {
#if __has_builtin(__builtin_amdgcn_fdot2)
    return __builtin_amdgcn_fdot2(a, b, c, false);
#else
    return c + (float)a.x * (float)b.x + (float)a.y * (float)b.y;
#endif
}

// ---------------------------------------------------------------------------
// CSR build: histogram -> single-block scan -> scatter
// ---------------------------------------------------------------------------
__global__ __launch_bounds__(256) void hist_kernel(
    const int* __restrict__ dst, int* __restrict__ cnt, int E)
{
    for (int e = blockIdx.x * 256 + threadIdx.x; e < E; e += gridDim.x * 256)
        atomicAdd(&cnt[dst[e]], 1);
}

__global__ __launch_bounds__(1024) void scan_kernel(
    const int* __restrict__ cnt, int* __restrict__ off,
    int* __restrict__ cur, int n, int chunk)
{
    __shared__ int part[1024];
    const int t = threadIdx.x;
    const int b = t * chunk;
    const int e = min(b + chunk, n);
    int s = 0;
    for (int i = b; i < e; ++i) s += cnt[i];
    part[t] = s;
    __syncthreads();
    for (int d = 1; d < 1024; d <<= 1) {
        const int v = (t >= d) ? part[t - d] : 0;
        __syncthreads();
        part[t] += v;
        __syncthreads();
    }
    int run = (t > 0) ? part[t - 1] : 0;
    for (int i = b; i < e; ++i) {
        off[i] = run;
        cur[i] = run;
        run += cnt[i];
    }
    if (t == 1023) off[n] = run;
}

__global__ __launch_bounds__(256) void scatter_kernel(
    const int* __restrict__ src, const int* __restrict__ dst,
    int* __restrict__ cur, int* __restrict__ srcs,
    int* __restrict__ csr_eid, int E)
{
    for (int e = blockIdx.x * 256 + threadIdx.x; e < E; e += gridDim.x * 256) {
        const int p = atomicAdd(&cur[dst[e]], 1);
        srcs[p]    = src[e];
        csr_eid[p] = e;
    }
}

// ---------------------------------------------------------------------------
// Permute edge_attr into CSR order, fp16 rows (E x 32 halfs = E x 4 uint4).
// ---------------------------------------------------------------------------
__global__ __launch_bounds__(256) void ea_permute_kernel(
    const float* __restrict__ ea, const int* __restrict__ csr_eid,
    uint4* __restrict__ ea16q, int E)
{
    const int idx = blockIdx.x * 256 + threadIdx.x;
    const int p = idx >> 2;
    if (p >= E) return;
    const int q = idx & 3;
    const int eid = csr_eid[p];
    const float4 a = *(const float4*)(ea + (size_t)eid * EDGE_DIM + q * 8);
    const float4 b = *(const float4*)(ea + (size_t)eid * EDGE_DIM + q * 8 + 4);
    uint4 o;
    o.x = pk2h(a.x, a.y); o.y = pk2h(a.z, a.w);
    o.z = pk2h(b.x, b.y); o.w = pk2h(b.z, b.w);
    ea16q[(size_t)p * 4 + q] = o;
}

// ---------------------------------------------------------------------------
// W_lin (32x128 fp32) -> k-pair-packed fp16: wl16d[kp*128 + c] =
// pack(W[2kp][c], W[2kp+1][c]), kp = 0..15.
// ---------------------------------------------------------------------------
__global__ __launch_bounds__(256) void wl_build_kernel(
    const float* __restrict__ Wl, unsigned* __restrict__ wl16d)
{
#pragma unroll
    for (int r = 0; r < 8; ++r) {
        const int idx = r * 256 + threadIdx.x;
        const int kp = idx >> 7, c = idx & 127;
        wl16d[idx] = pk2h(Wl[(2 * kp) * D_DIM + c], Wl[(2 * kp + 1) * D_DIM + c]);
    }
}

// ---------------------------------------------------------------------------
// xprep: x16 = fp16( XFORM ? relu(h*sc+sh) : h )  (prev layer's BN folded)
// ---------------------------------------------------------------------------
template<int XFORM>
__global__ __launch_bounds__(256) void xprep_kernel(
    const float* __restrict__ h, const float* __restrict__ scsh,
    uint2* __restrict__ x16q, int M)
{
    __shared__ float sc[128], sh[128];
    if (XFORM) {
        if (threadIdx.x < 128) {
            sc[threadIdx.x] = scsh[threadIdx.x];
            sh[threadIdx.x] = scsh[128 + threadIdx.x];
        }
        __syncthreads();
    }
    const int total = M * 32;
    for (int i = blockIdx.x * 256 + threadIdx.x; i < total; i += gridDim.x * 256) {
        float4 v = ((const float4*)h)[i];
        if (XFORM) {
            const int c = (i & 31) * 4;
            v.x = fmaxf(fmaf(v.x, sc[c + 0], sh[c + 0]), 0.f);
            v.y = fmaxf(fmaf(v.y, sc[c + 1], sh[c + 1]), 0.f);
            v.z = fmaxf(fmaf(v.z, sc[c + 2], sh[c + 2]), 0.f);
            v.w = fmaxf(fmaf(v.w, sc[c + 3], sh[c + 3]), 0.f);
        }
        uint2 o; o.x = pk2h(v.x, v.y); o.y = pk2h(v.z, v.w);
        x16q[i] = o;
    }
}

// ---------------------------------------------------------------------------
// Edge aggregation: one wave per node, fp16 gather + fdot2 matvec, no atomics.
//   agg[n] = sum_{e in in(n)} relu(x16[src_e] + ea16[p] @ W_lin + b_lin)
// Lane owns cols {2*lane, 2*lane+1}.
// ---------------------------------------------------------------------------
__global__ __launch_bounds__(256) void edge_agg_kernel(
    const unsigned* __restrict__ x16d,     // N x 64 dwords
    const int*      __restrict__ srcs,     // E (CSR order)
    const uint4*    __restrict__ ea16q,    // E x 4 (CSR order)
    const int*      __restrict__ row_off,
    const unsigned* __restrict__ wl16d,    // 16 x 128 dwords
    const float*    __restrict__ bl,
    float*          __restrict__ agg,
    int nNodes)
{
    const int lane = threadIdx.x & 63;
    const int wid  = threadIdx.x >> 6;

    unsigned wA[16], wB[16];
#pragma unroll
    for (int kp = 0; kp < 16; ++kp) {
        const uint2 w2 = *(const uint2*)(wl16d + kp * 128 + 2 * lane);
        wA[kp] = w2.x; wB[kp] = w2.y;
    }
    const float b0 = bl[2 * lane];
    const float b1 = bl[2 * lane + 1];

    const int stride = gridDim.x * 4;
    for (int node = blockIdx.x * 4 + wid; node < nNodes; node += stride) {
        const int beg = __builtin_amdgcn_readfirstlane(row_off[node]);
        const int end = __builtin_amdgcn_readfirstlane(row_off[node + 1]);
        float acc0 = 0.f, acc1 = 0.f;

        auto edge_body = [&](int p) {
            const int s = srcs[p];
            const uint4 q0 = ea16q[(size_t)p * 4 + 0];
            const uint4 q1 = ea16q[(size_t)p * 4 + 1];
            const uint4 q2 = ea16q[(size_t)p * 4 + 2];
            const uint4 q3 = ea16q[(size_t)p * 4 + 3];
            const unsigned xd = x16d[(size_t)s * 64 + lane];
            const unsigned aw[16] = {q0.x, q0.y, q0.z, q0.w,
                                     q1.x, q1.y, q1.z, q1.w,
                                     q2.x, q2.y, q2.z, q2.w,
                                     q3.x, q3.y, q3.z, q3.w};
            float e0 = b0, e1 = b1;
#pragma unroll
            for (int kp = 0; kp < 16; ++kp) {
                e0 = fdot2f(asH2(aw[kp]), asH2(wA[kp]), e0);
                e1 = fdot2f(asH2(aw[kp]), asH2(wB[kp]), e1);
            }
            const half2v xh = asH2(xd);
            acc0 += fmaxf((float)xh.x + e0, 0.f);
            acc1 += fmaxf((float)xh.y + e1, 0.f);
        };

        int j = beg;
        if ((end - beg) & 1) { edge_body(j); ++j; }
#pragma unroll 1
        for (; j < end; j += 2) {
            edge_body(j);
            edge_body(j + 1);
        }
        *(float2*)(agg + (size_t)node * D_DIM + 2 * lane) = make_float2(acc0, acc1);
    }
}

// ---------------------------------------------------------------------------
// MFMA GEMM 1: h1 = relu( (x16 + agg) @ W1 + b1 )  -> fp16 output
// ---------------------------------------------------------------------------
__global__ __launch_bounds__(256) void gemm1_kernel(
    const unsigned* __restrict__ x16d,
    const float* __restrict__ agg,
    const float* __restrict__ W,
    const float* __restrict__ bias,
    ushort_t* __restrict__ h1,
    int M)
{
    __shared__ char ATb[128 * 256];
    __shared__ char WTb[128 * 256];
    const int tid = threadIdx.x;
    const int m0  = blockIdx.x * 128;

#pragma unroll
    for (int i = 0; i < 16; ++i) {
        const int idx = i * 256 + tid;
        const int r = idx >> 5, c4 = idx & 31;
        const int row = m0 + r;
        f32x4 v = {0.f, 0.f, 0.f, 0.f};
        if (row < M) {
            const uint2 xv = *(const uint2*)(x16d + (size_t)row * 64 + c4 * 2);
            const f32x4 g  = *(const f32x4*)(agg + (size_t)row * 128 + c4 * 4);
            const half2v xa = asH2(xv.x), xb = asH2(xv.y);
            v[0] = (float)xa.x + g[0];
            v[1] = (float)xa.y + g[1];
            v[2] = (float)xb.x + g[2];
            v[3] = (float)xb.y + g[3];
        }
        uint2 p; p.x = pk2h(v[0], v[1]); p.y = pk2h(v[2], v[3]);
        *(uint2*)(ATb + r * 256 + ((c4 * 8) ^ ((r & 7) << 4))) = p;
    }
#pragma unroll
    for (int i = 0; i < 8; ++i) {
        const int c4 = (tid >> 6) + 4 * i;
        const int kp = tid & 63;
        const f32x4 wa = *(const f32x4*)(W + (size_t)(2 * kp) * 128 + c4 * 4);
        const f32x4 wb = *(const f32x4*)(W + (size_t)(2 * kp + 1) * 128 + c4 * 4);
#pragma unroll
        for (int j = 0; j < 4; ++j) {
            const int col = c4 * 4 + j;
            *(unsigned*)(WTb + col * 256 + ((kp * 4) ^ ((col & 7) << 4))) = pk2h(wa[j], wb[j]);
        }
    }
    __syncthreads();

    const int lane = tid & 63;
    const int w    = tid >> 6;
    const int fr   = lane & 15;
    const int fg   = lane >> 4;

    f32x4 acc[2][8];
#pragma unroll
    for (int a = 0; a < 2; ++a)
#pragma unroll
        for (int b = 0; b < 8; ++b) acc[a][b] = (f32x4){0.f, 0.f, 0.f, 0.f};

    const int ar0 = w * 32 + fr;
    const int asz = (ar0 & 7) << 4;
#pragma unroll
    for (int ks = 0; ks < 4; ++ks) {
        const int kb = ks * 64 + fg * 16;
        const f16x8 a0 = *(const f16x8*)(ATb + ar0 * 256 + (kb ^ asz));
        const f16x8 a1 = *(const f16x8*)(ATb + (ar0 + 16) * 256 + (kb ^ asz));
#pragma unroll
        for (int cb = 0; cb < 8; ++cb) {
            const int col = cb * 16 + fr;
            const f16x8 b = *(const f16x8*)(WTb + col * 256 + (kb ^ ((col & 7) << 4)));
            acc[0][cb] = __builtin_amdgcn_mfma_f32_16x16x32_f16(a0, b, acc[0][cb], 0, 0, 0);
            acc[1][cb] = __builtin_amdgcn_mfma_f32_16x16x32_f16(a1, b, acc[1][cb], 0, 0, 0);
        }
    }

    float bv[8];
#pragma unroll
    for (int cb = 0; cb < 8; ++cb) bv[cb] = bias[cb * 16 + fr];
#pragma unroll
    for (int rf = 0; rf < 2; ++rf) {
        const int r0 = m0 + w * 32 + rf * 16 + fg * 4;
#pragma unroll
        for (int cb = 0; cb < 8; ++cb) {
            const int col = cb * 16 + fr;
#pragma unroll
            for (int j = 0; j < 4; ++j) {
                const int row = r0 + j;
                if (row < M) {
                    const float v = fmaxf(acc[rf][cb][j] + bv[cb], 0.f);
                    h1[(size_t)row * 128 + col] = f2h(v);
                }
            }
        }
    }
}

// ---------------------------------------------------------------------------
// MFMA GEMM 2: h = h1 @ W2 + b2 (fp32 out) + fused BN column sums/sumsq.
// ---------------------------------------------------------------------------
__global__ __launch_bounds__(256) void gemm2_kernel(
    const ushort_t* __restrict__ h1,
    const float* __restrict__ W,
    const float* __restrict__ bias,
    float* __restrict__ C,
    float* __restrict__ sums,
    int M)
{
    __shared__ char ATb[128 * 256];
    __shared__ char WTb[128 * 256];
    __shared__ float bsum[256];
    const int tid = threadIdx.x;
    const int m0  = blockIdx.x * 128;

    bsum[tid] = 0.f;

#pragma unroll
    for (int i = 0; i < 8; ++i) {
        const int idx = i * 256 + tid;
        const int r = idx >> 4, c8 = idx & 15;
        const int row = m0 + r;
        uint4 v = make_uint4(0u, 0u, 0u, 0u);
        if (row < M) v = *(const uint4*)(h1 + (size_t)row * 128 + c8 * 8);
        *(uint4*)(ATb + r * 256 + ((c8 * 16) ^ ((r & 7) << 4))) = v;
    }
#pragma unroll
    for (int i = 0; i < 8; ++i) {
        const int c4 = (tid >> 6) + 4 * i;
        const int kp = tid & 63;
        const f32x4 wa = *(const f32x4*)(W + (size_t)(2 * kp) * 128 + c4 * 4);
        const f32x4 wb = *(const f32x4*)(W + (size_t)(2 * kp + 1) * 128 + c4 * 4);
#pragma unroll
        for (int j = 0; j < 4; ++j) {
            const int col = c4 * 4 + j;
            *(unsigned*)(WTb + col * 256 + ((kp * 4) ^ ((col & 7) << 4))) = pk2h(wa[j], wb[j]);
        }
    }
    __syncthreads();

    const int lane = tid & 63;
    const int w    = tid >> 6;
    const int fr   = lane & 15;
    const int fg   = lane >> 4;

    f32x4 acc[2][8];
#pragma unroll
    for (int a = 0; a < 2; ++a)
#pragma unroll
        for (int b = 0; b < 8; ++b) acc[a][b] = (f32x4){0.f, 0.f, 0.f, 0.f};

    const int ar0 = w * 32 + fr;
    const int asz = (ar0 & 7) << 4;
#pragma unroll
    for (int ks = 0; ks < 4; ++ks) {
        const int kb = ks * 64 + fg * 16;
        const f16x8 a0 = *(const f16x8*)(ATb + ar0 * 256 + (kb ^ asz));
        const f16x8 a1 = *(const f16x8*)(ATb + (ar0 + 16) * 256 + (kb ^ asz));
#pragma unroll
        for (int cb = 0; cb < 8; ++cb) {
            const int col = cb * 16 + fr;
            const f16x8 b = *(const f16x8*)(WTb + col * 256 + (kb ^ ((col & 7) << 4)));
            acc[0][cb] = __builtin_amdgcn_mfma_f32_16x16x32_f16(a0, b, acc[0][cb], 0, 0, 0);
            acc[1][cb] = __builtin_amdgcn_mfma_f32_16x16x32_f16(a1, b, acc[1][cb], 0, 0, 0);
        }
    }

    float bv[8];
#pragma unroll
    for (int cb = 0; cb < 8; ++cb) bv[cb] = bias[cb * 16 + fr];
    float s[8], q[8];
#pragma unroll
    for (int cb = 0; cb < 8; ++cb) { s[cb] = 0.f; q[cb] = 0.f; }

#pragma unroll
    for (int rf = 0; rf < 2; ++rf) {
        const int r0 = m0 + w * 32 + rf * 16 + fg * 4;
#pragma unroll
        for (int cb = 0; cb < 8; ++cb) {
            const int col = cb * 16 + fr;
#pragma unroll
            for (int j = 0; j < 4; ++j) {
                const int row = r0 + j;
                if (row < M) {
                    const float v = acc[rf][cb][j] + bv[cb];
                    C[(size_t)row * 128 + col] = v;
                    s[cb] += v;
                    q[cb] += v * v;
                }
            }
        }
    }
#pragma unroll
    for (int cb = 0; cb < 8; ++cb) {
        float ss = s[cb]; ss += __shfl_down(ss, 32); ss += __shfl_down(ss, 16);
        float qq = q[cb]; qq += __shfl_down(qq, 32); qq += __shfl_down(qq, 16);
        if (lane < 16) {
            atomicAdd(&bsum[cb * 16 + lane], ss);
            atomicAdd(&bsum[128 + cb * 16 + lane], qq);
        }
    }
    __syncthreads();
    unsafeAtomicAdd(&sums[tid], bsum[tid]);
}

// ---------------------------------------------------------------------------
__global__ __launch_bounds__(128) void bn_finalize_kernel(
    const float* __restrict__ sums,
    const float* __restrict__ gamma, const float* __restrict__ beta,
    float* __restrict__ scsh, float invM)
{
    const int c = threadIdx.x;
    const float mu  = sums[c] * invM;
    const float var = sums[128 + c] * invM - mu * mu;
    const float sc  = gamma[c] * rsqrtf(var + BN_EPS);
    scsh[c]       = sc;
    scsh[128 + c] = beta[c] - mu * sc;
}

__global__ __launch_bounds__(256) void bn_apply_final(
    float* __restrict__ h, const float* __restrict__ scsh, int M)
{
    __shared__ float sc[128], sh[128];
    if (threadIdx.x < 128) {
        sc[threadIdx.x] = scsh[threadIdx.x];
        sh[threadIdx.x] = scsh[128 + threadIdx.x];
    }
    __syncthreads();
    const size_t total = (size_t)M * D_DIM / 4;
    for (size_t i = (size_t)blockIdx.x * 256 + threadIdx.x; i < total;
         i += (size_t)gridDim.x * 256) {
        float4 v = ((const float4*)h)[i];
        const int cb = ((int)(i & 31)) * 4;
        v.x = fmaxf(fmaf(v.x, sc[cb + 0], sh[cb + 0]), 0.f);
        v.y = fmaxf(fmaf(v.y, sc[cb + 1], sh[cb + 1]), 0.f);
        v.z = fmaxf(fmaf(v.z, sc[cb + 2], sh[cb + 2]), 0.f);
        v.w = fmaxf(fmaf(v.w, sc[cb + 3], sh[cb + 3]), 0.f);
        ((float4*)h)[i] = v;
    }
}

// ---------------------------------------------------------------------------
extern "C" void kernel_launch(void* const* d_in, const int* in_sizes, int n_in,
                              void* d_out, int out_size, void* d_ws, size_t ws_size,
                              hipStream_t stream)
{
    const float* x_in  = (const float*)d_in[0];
    const int*   ei    = (const int*)  d_in[1];
    const float* ea    = (const float*)d_in[2];
    const float* W_lin = (const float*)d_in[3];
    const float* b_lin = (const float*)d_in[4];
    const float* W1    = (const float*)d_in[5];
    const float* b1    = (const float*)d_in[6];
    const float* W2    = (const float*)d_in[7];
    const float* b2    = (const float*)d_in[8];
    const float* gamma = (const float*)d_in[9];
    const float* beta  = (const float*)d_in[10];

    const int N = in_sizes[0] / D_DIM;              // 50000
    const int E = in_sizes[2] / EDGE_DIM;           // 600000
    const int L = in_sizes[3] / (EDGE_DIM * D_DIM); // 3

    const int* src = ei;
    const int* dst = ei + E;

    float* out = (float*)d_out;

    // ---- ws layout (16B-aligned regions) ----
    char* wp = (char*)d_ws;
    auto take = [&wp](size_t bytes) {
        char* r = wp;
        wp += (bytes + 15) & ~(size_t)15;
        return r;
    };
    float*     agg     = (float*)    take((size_t)N * D_DIM * 4);
    ushort_t*  h1      = (ushort_t*) take((size_t)N * D_DIM * 2);
    unsigned*  x16d    = (unsigned*) take((size_t)N * D_DIM * 2);
    float*     sums    = (float*)    take(256 * 4);
    float*     scsh    = (float*)    take(256 * 4);
    unsigned*  wl16d   = (unsigned*) take(16 * 128 * 4);
    int*       cnt     = (int*)      take((size_t)N * 4);
    int*       row_off = (int*)      take((size_t)(N + 1) * 4);
    int*       cur     = (int*)      take((size_t)N * 4);
    int*       srcs    = (int*)      take((size_t)E * 4);
    int*       csr_eid = (int*)      take((size_t)E * 4);
    uint4*     ea16q   = (uint4*)    take((size_t)E * 64);

    const int gemmBlocks = (N + 127) / 128;

    // ---- CSR build + edge_attr fp16 permute (once per call) ----
    hipMemsetAsync(cnt, 0, (size_t)N * sizeof(int), stream);
    hist_kernel<<<1024, 256, 0, stream>>>(dst, cnt, E);
    scan_kernel<<<1, 1024, 0, stream>>>(cnt, row_off, cur, N, (N + 1023) / 1024);
    scatter_kernel<<<1024, 256, 0, stream>>>(src, dst, cur, srcs, csr_eid, E);
    ea_permute_kernel<<<(E * 4 + 255) / 256, 256, 0, stream>>>(ea, csr_eid, ea16q, E);

    for (int l = 0; l < L; ++l) {
        hipMemsetAsync(sums, 0, 256 * sizeof(float), stream);

        const float* Wl_l = W_lin + (size_t)l * EDGE_DIM * D_DIM;
        const float* bl_l = b_lin + (size_t)l * D_DIM;
        const float* W1_l = W1 + (size_t)l * D_DIM * D_DIM;
        const float* b1_l = b1 + (size_t)l * D_DIM;
        const float* W2_l = W2 + (size_t)l * D_DIM * D_DIM;
        const float* b2_l = b2 + (size_t)l * D_DIM;

        if (l == 0)
            xprep_kernel<0><<<2048, 256, 0, stream>>>(x_in, nullptr, (uint2*)x16d, N);
        else
            xprep_kernel<1><<<2048, 256, 0, stream>>>(out, scsh, (uint2*)x16d, N);

        wl_build_kernel<<<1, 256, 0, stream>>>(Wl_l, wl16d);

        edge_agg_kernel<<<2048, 256, 0, stream>>>(
            x16d, srcs, ea16q, row_off, wl16d, bl_l, agg, N);

        gemm1_kernel<<<gemmBlocks, 256, 0, stream>>>(
            x16d, agg, W1_l, b1_l, h1, N);

        gemm2_kernel<<<gemmBlocks, 256, 0, stream>>>(
            h1, W2_l, b2_l, out, sums, N);

        bn_finalize_kernel<<<1, 128, 0, stream>>>(
            sums, gamma + (size_t)l * D_DIM, beta + (size_t)l * D_DIM,
            scsh, 1.f / (float)N);
    }

    bn_apply_final<<<2048, 256, 0, stream>>>(out, scsh, N);
}

// Round 6
// 480.598 us; speedup vs baseline: 1.7851x; 1.2084x over previous
//
#include <hip/hip_runtime.h>

#define D_DIM 128
#define EDGE_DIM 32
#define BN_EPS 1e-5f

typedef __attribute__((ext_vector_type(8))) _Float16 f16x8;
typedef __attribute__((ext_vector_type(2))) _Float16 half2v;
typedef __attribute__((ext_vector_type(4))) float f32x4;
typedef unsigned short ushort_t;

__device__ __forceinline__ unsigned short f2h(float f) {
    union { _Float16 h; unsigned short u; } c;
    c.h = (_Float16)f;
    return c.u;
}
__device__ __forceinline__ unsigned pk2h(float lo, float hi) {
    return (unsigned)f2h(lo) | ((unsigned)f2h(hi) << 16);
}
__device__ __forceinline__ half2v asH2(unsigned u) {
    union { unsigned u; half2v h; } c;
    c.u = u;
    return c.h;
}
__device__ __forceinline__ float fdot2f(half2v a, half2v b, float c) {
#if __has_builtin(__builtin_amdgcn_fdot2)
    return __builtin_amdgcn_fdot2(a, b, c, false);
#else
    return c + (float)a.x * (float)b.x + (float)a.y * (float)b.y;
#endif
}

// ---------------------------------------------------------------------------
// CSR build: histogram -> multi-block scan -> scatter
// ---------------------------------------------------------------------------
__global__ __launch_bounds__(256) void hist_kernel(
    const int* __restrict__ dst, int* __restrict__ cnt, int E)
{
    for (int e = blockIdx.x * 256 + threadIdx.x; e < E; e += gridDim.x * 256)
        atomicAdd(&cnt[dst[e]], 1);
}

// Tile = 2048 elements/block (256 threads x 8). Writes tile-local exclusive
// offsets to off and the block total to blksum.
__global__ __launch_bounds__(256) void scan_local_kernel(
    const int* __restrict__ cnt, int* __restrict__ off,
    int* __restrict__ blksum, int n)
{
    __shared__ int part[256];
    const int t = threadIdx.x;
    const int base = blockIdx.x * 2048 + t * 8;
    int v[8];
    int s = 0;
#pragma unroll
    for (int j = 0; j < 8; ++j) {
        const int idx = base + j;
        const int c = (idx < n) ? cnt[idx] : 0;
        v[j] = s;
        s += c;
    }
    part[t] = s;
    __syncthreads();
    for (int d = 1; d < 256; d <<= 1) {
        const int val = (t >= d) ? part[t - d] : 0;
        __syncthreads();
        part[t] += val;
        __syncthreads();
    }
    const int texcl = (t > 0) ? part[t - 1] : 0;
#pragma unroll
    for (int j = 0; j < 8; ++j) {
        const int idx = base + j;
        if (idx < n) off[idx] = texcl + v[j];
    }
    if (t == 255) blksum[blockIdx.x] = part[255];
}

// Serial exclusive scan of B block totals (B ~ 25): converts blksum in place,
// writes grand total to off[n].
__global__ __launch_bounds__(64) void scan_tops_kernel(
    int* __restrict__ blksum, int* __restrict__ off, int n, int B)
{
    if (threadIdx.x == 0) {
        int run = 0;
        for (int b = 0; b < B; ++b) {
            const int v = blksum[b];
            blksum[b] = run;
            run += v;
        }
        off[n] = run;
    }
}

// Adds block offset; writes final off and cur.
__global__ __launch_bounds__(256) void scan_add_kernel(
    int* __restrict__ off, int* __restrict__ cur,
    const int* __restrict__ blksum, int n)
{
    const int base = blockIdx.x * 2048;
    const int add = blksum[blockIdx.x];
    for (int j = threadIdx.x; j < 2048; j += 256) {
        const int i = base + j;
        if (i < n) {
            const int v = off[i] + add;
            off[i] = v;
            cur[i] = v;
        }
    }
}

__global__ __launch_bounds__(256) void scatter_kernel(
    const int* __restrict__ src, const int* __restrict__ dst,
    int* __restrict__ cur, int* __restrict__ srcs,
    int* __restrict__ csr_eid, int E)
{
    for (int e = blockIdx.x * 256 + threadIdx.x; e < E; e += gridDim.x * 256) {
        const int p = atomicAdd(&cur[dst[e]], 1);
        srcs[p]    = src[e];
        csr_eid[p] = e;
    }
}

// ---------------------------------------------------------------------------
// Permute edge_attr into CSR order, fp16 rows (E x 32 halfs = E x 4 uint4).
// ---------------------------------------------------------------------------
__global__ __launch_bounds__(256) void ea_permute_kernel(
    const float* __restrict__ ea, const int* __restrict__ csr_eid,
    uint4* __restrict__ ea16q, int E)
{
    const int idx = blockIdx.x * 256 + threadIdx.x;
    const int p = idx >> 2;
    if (p >= E) return;
    const int q = idx & 3;
    const int eid = csr_eid[p];
    const float4 a = *(const float4*)(ea + (size_t)eid * EDGE_DIM + q * 8);
    const float4 b = *(const float4*)(ea + (size_t)eid * EDGE_DIM + q * 8 + 4);
    uint4 o;
    o.x = pk2h(a.x, a.y); o.y = pk2h(a.z, a.w);
    o.z = pk2h(b.x, b.y); o.w = pk2h(b.z, b.w);
    ea16q[(size_t)p * 4 + q] = o;
}

// ---------------------------------------------------------------------------
// W_lin (32x128 fp32) -> k-pair-packed fp16: wl16d[kp*128 + c] =
// pack(W[2kp][c], W[2kp+1][c]), kp = 0..15.
// ---------------------------------------------------------------------------
__global__ __launch_bounds__(256) void wl_build_kernel(
    const float* __restrict__ Wl, unsigned* __restrict__ wl16d)
{
#pragma unroll
    for (int r = 0; r < 8; ++r) {
        const int idx = r * 256 + threadIdx.x;
        const int kp = idx >> 7, c = idx & 127;
        wl16d[idx] = pk2h(Wl[(2 * kp) * D_DIM + c], Wl[(2 * kp + 1) * D_DIM + c]);
    }
}

// ---------------------------------------------------------------------------
// xprep: x16 = fp16( XFORM ? relu(h*sc+sh) : h )  (prev layer's BN folded)
// ---------------------------------------------------------------------------
template<int XFORM>
__global__ __launch_bounds__(256) void xprep_kernel(
    const float* __restrict__ h, const float* __restrict__ scsh,
    uint2* __restrict__ x16q, int M)
{
    __shared__ float sc[128], sh[128];
    if (XFORM) {
        if (threadIdx.x < 128) {
            sc[threadIdx.x] = scsh[threadIdx.x];
            sh[threadIdx.x] = scsh[128 + threadIdx.x];
        }
        __syncthreads();
    }
    const int total = M * 32;
    for (int i = blockIdx.x * 256 + threadIdx.x; i < total; i += gridDim.x * 256) {
        float4 v = ((const float4*)h)[i];
        if (XFORM) {
            const int c = (i & 31) * 4;
            v.x = fmaxf(fmaf(v.x, sc[c + 0], sh[c + 0]), 0.f);
            v.y = fmaxf(fmaf(v.y, sc[c + 1], sh[c + 1]), 0.f);
            v.z = fmaxf(fmaf(v.z, sc[c + 2], sh[c + 2]), 0.f);
            v.w = fmaxf(fmaf(v.w, sc[c + 3], sh[c + 3]), 0.f);
        }
        uint2 o; o.x = pk2h(v.x, v.y); o.y = pk2h(v.z, v.w);
        x16q[i] = o;
    }
}

// ---------------------------------------------------------------------------
// Edge aggregation: one wave per node, fp16 gather + fdot2 matvec, no atomics.
//   agg[n] = sum_{e in in(n)} relu(x16[src_e] + ea16[p] @ W_lin + b_lin)
// Lane owns cols {2*lane, 2*lane+1}.
// ---------------------------------------------------------------------------
__global__ __launch_bounds__(256) void edge_agg_kernel(
    const unsigned* __restrict__ x16d,     // N x 64 dwords
    const int*      __restrict__ srcs,     // E (CSR order)
    const uint4*    __restrict__ ea16q,    // E x 4 (CSR order)
    const int*      __restrict__ row_off,
    const unsigned* __restrict__ wl16d,    // 16 x 128 dwords
    const float*    __restrict__ bl,
    float*          __restrict__ agg,
    int nNodes)
{
    const int lane = threadIdx.x & 63;
    const int wid  = threadIdx.x >> 6;

    unsigned wA[16], wB[16];
#pragma unroll
    for (int kp = 0; kp < 16; ++kp) {
        const uint2 w2 = *(const uint2*)(wl16d + kp * 128 + 2 * lane);
        wA[kp] = w2.x; wB[kp] = w2.y;
    }
    const float b0 = bl[2 * lane];
    const float b1 = bl[2 * lane + 1];

    const int stride = gridDim.x * 4;
    for (int node = blockIdx.x * 4 + wid; node < nNodes; node += stride) {
        const int beg = __builtin_amdgcn_readfirstlane(row_off[node]);
        const int end = __builtin_amdgcn_readfirstlane(row_off[node + 1]);
        float acc0 = 0.f, acc1 = 0.f;

        auto edge_body = [&](int p) {
            const int s = srcs[p];
            const uint4 q0 = ea16q[(size_t)p * 4 + 0];
            const uint4 q1 = ea16q[(size_t)p * 4 + 1];
            const uint4 q2 = ea16q[(size_t)p * 4 + 2];
            const uint4 q3 = ea16q[(size_t)p * 4 + 3];
            const unsigned xd = x16d[(size_t)s * 64 + lane];
            const unsigned aw[16] = {q0.x, q0.y, q0.z, q0.w,
                                     q1.x, q1.y, q1.z, q1.w,
                                     q2.x, q2.y, q2.z, q2.w,
                                     q3.x, q3.y, q3.z, q3.w};
            float e0 = b0, e1 = b1;
#pragma unroll
            for (int kp = 0; kp < 16; ++kp) {
                e0 = fdot2f(asH2(aw[kp]), asH2(wA[kp]), e0);
                e1 = fdot2f(asH2(aw[kp]), asH2(wB[kp]), e1);
            }
            const half2v xh = asH2(xd);
            acc0 += fmaxf((float)xh.x + e0, 0.f);
            acc1 += fmaxf((float)xh.y + e1, 0.f);
        };

        int j = beg;
        if ((end - beg) & 1) { edge_body(j); ++j; }
#pragma unroll 1
        for (; j < end; j += 2) {
            edge_body(j);
            edge_body(j + 1);
        }
        *(float2*)(agg + (size_t)node * D_DIM + 2 * lane) = make_float2(acc0, acc1);
    }
}

// ---------------------------------------------------------------------------
// MFMA GEMM 1: h1 = relu( (x16 + agg) @ W1 + b1 )  -> fp16 output
// ---------------------------------------------------------------------------
__global__ __launch_bounds__(256) void gemm1_kernel(
    const unsigned* __restrict__ x16d,
    const float* __restrict__ agg,
    const float* __restrict__ W,
    const float* __restrict__ bias,
    ushort_t* __restrict__ h1,
    int M)
{
    __shared__ char ATb[128 * 256];
    __shared__ char WTb[128 * 256];
    const int tid = threadIdx.x;
    const int m0  = blockIdx.x * 128;

#pragma unroll
    for (int i = 0; i < 16; ++i) {
        const int idx = i * 256 + tid;
        const int r = idx >> 5, c4 = idx & 31;
        const int row = m0 + r;
        f32x4 v = {0.f, 0.f, 0.f, 0.f};
        if (row < M) {
            const uint2 xv = *(const uint2*)(x16d + (size_t)row * 64 + c4 * 2);
            const f32x4 g  = *(const f32x4*)(agg + (size_t)row * 128 + c4 * 4);
            const half2v xa = asH2(xv.x), xb = asH2(xv.y);
            v[0] = (float)xa.x + g[0];
            v[1] = (float)xa.y + g[1];
            v[2] = (float)xb.x + g[2];
            v[3] = (float)xb.y + g[3];
        }
        uint2 p; p.x = pk2h(v[0], v[1]); p.y = pk2h(v[2], v[3]);
        *(uint2*)(ATb + r * 256 + ((c4 * 8) ^ ((r & 7) << 4))) = p;
    }
#pragma unroll
    for (int i = 0; i < 8; ++i) {
        const int c4 = (tid >> 6) + 4 * i;
        const int kp = tid & 63;
        const f32x4 wa = *(const f32x4*)(W + (size_t)(2 * kp) * 128 + c4 * 4);
        const f32x4 wb = *(const f32x4*)(W + (size_t)(2 * kp + 1) * 128 + c4 * 4);
#pragma unroll
        for (int j = 0; j < 4; ++j) {
            const int col = c4 * 4 + j;
            *(unsigned*)(WTb + col * 256 + ((kp * 4) ^ ((col & 7) << 4))) = pk2h(wa[j], wb[j]);
        }
    }
    __syncthreads();

    const int lane = tid & 63;
    const int w    = tid >> 6;
    const int fr   = lane & 15;
    const int fg   = lane >> 4;

    f32x4 acc[2][8];
#pragma unroll
    for (int a = 0; a < 2; ++a)
#pragma unroll
        for (int b = 0; b < 8; ++b) acc[a][b] = (f32x4){0.f, 0.f, 0.f, 0.f};

    const int ar0 = w * 32 + fr;
    const int asz = (ar0 & 7) << 4;
#pragma unroll
    for (int ks = 0; ks < 4; ++ks) {
        const int kb = ks * 64 + fg * 16;
        const f16x8 a0 = *(const f16x8*)(ATb + ar0 * 256 + (kb ^ asz));
        const f16x8 a1 = *(const f16x8*)(ATb + (ar0 + 16) * 256 + (kb ^ asz));
#pragma unroll
        for (int cb = 0; cb < 8; ++cb) {
            const int col = cb * 16 + fr;
            const f16x8 b = *(const f16x8*)(WTb + col * 256 + (kb ^ ((col & 7) << 4)));
            acc[0][cb] = __builtin_amdgcn_mfma_f32_16x16x32_f16(a0, b, acc[0][cb], 0, 0, 0);
            acc[1][cb] = __builtin_amdgcn_mfma_f32_16x16x32_f16(a1, b, acc[1][cb], 0, 0, 0);
        }
    }

    float bv[8];
#pragma unroll
    for (int cb = 0; cb < 8; ++cb) bv[cb] = bias[cb * 16 + fr];
#pragma unroll
    for (int rf = 0; rf < 2; ++rf) {
        const int r0 = m0 + w * 32 + rf * 16 + fg * 4;
#pragma unroll
        for (int cb = 0; cb < 8; ++cb) {
            const int col = cb * 16 + fr;
#pragma unroll
            for (int j = 0; j < 4; ++j) {
                const int row = r0 + j;
                if (row < M) {
                    const float v = fmaxf(acc[rf][cb][j] + bv[cb], 0.f);
                    h1[(size_t)row * 128 + col] = f2h(v);
                }
            }
        }
    }
}

// ---------------------------------------------------------------------------
// MFMA GEMM 2: h = h1 @ W2 + b2 (fp32 out) + fused BN column sums/sumsq.
// ---------------------------------------------------------------------------
__global__ __launch_bounds__(256) void gemm2_kernel(
    const ushort_t* __restrict__ h1,
    const float* __restrict__ W,
    const float* __restrict__ bias,
    float* __restrict__ C,
    float* __restrict__ sums,
    int M)
{
    __shared__ char ATb[128 * 256];
    __shared__ char WTb[128 * 256];
    __shared__ float bsum[256];
    const int tid = threadIdx.x;
    const int m0  = blockIdx.x * 128;

    bsum[tid] = 0.f;

#pragma unroll
    for (int i = 0; i < 8; ++i) {
        const int idx = i * 256 + tid;
        const int r = idx >> 4, c8 = idx & 15;
        const int row = m0 + r;
        uint4 v = make_uint4(0u, 0u, 0u, 0u);
        if (row < M) v = *(const uint4*)(h1 + (size_t)row * 128 + c8 * 8);
        *(uint4*)(ATb + r * 256 + ((c8 * 16) ^ ((r & 7) << 4))) = v;
    }
#pragma unroll
    for (int i = 0; i < 8; ++i) {
        const int c4 = (tid >> 6) + 4 * i;
        const int kp = tid & 63;
        const f32x4 wa = *(const f32x4*)(W + (size_t)(2 * kp) * 128 + c4 * 4);
        const f32x4 wb = *(const f32x4*)(W + (size_t)(2 * kp + 1) * 128 + c4 * 4);
#pragma unroll
        for (int j = 0; j < 4; ++j) {
            const int col = c4 * 4 + j;
            *(unsigned*)(WTb + col * 256 + ((kp * 4) ^ ((col & 7) << 4))) = pk2h(wa[j], wb[j]);
        }
    }
    __syncthreads();

    const int lane = tid & 63;
    const int w    = tid >> 6;
    const int fr   = lane & 15;
    const int fg   = lane >> 4;

    f32x4 acc[2][8];
#pragma unroll
    for (int a = 0; a < 2; ++a)
#pragma unroll
        for (int b = 0; b < 8; ++b) acc[a][b] = (f32x4){0.f, 0.f, 0.f, 0.f};

    const int ar0 = w * 32 + fr;
    const int asz = (ar0 & 7) << 4;
#pragma unroll
    for (int ks = 0; ks < 4; ++ks) {
        const int kb = ks * 64 + fg * 16;
        const f16x8 a0 = *(const f16x8*)(ATb + ar0 * 256 + (kb ^ asz));
        const f16x8 a1 = *(const f16x8*)(ATb + (ar0 + 16) * 256 + (kb ^ asz));
#pragma unroll
        for (int cb = 0; cb < 8; ++cb) {
            const int col = cb * 16 + fr;
            const f16x8 b = *(const f16x8*)(WTb + col * 256 + (kb ^ ((col & 7) << 4)));
            acc[0][cb] = __builtin_amdgcn_mfma_f32_16x16x32_f16(a0, b, acc[0][cb], 0, 0, 0);
            acc[1][cb] = __builtin_amdgcn_mfma_f32_16x16x32_f16(a1, b, acc[1][cb], 0, 0, 0);
        }
    }

    float bv[8];
#pragma unroll
    for (int cb = 0; cb < 8; ++cb) bv[cb] = bias[cb * 16 + fr];
    float s[8], q[8];
#pragma unroll
    for (int cb = 0; cb < 8; ++cb) { s[cb] = 0.f; q[cb] = 0.f; }

#pragma unroll
    for (int rf = 0; rf < 2; ++rf) {
        const int r0 = m0 + w * 32 + rf * 16 + fg * 4;
#pragma unroll
        for (int cb = 0; cb < 8; ++cb) {
            const int col = cb * 16 + fr;
#pragma unroll
            for (int j = 0; j < 4; ++j) {
                const int row = r0 + j;
                if (row < M) {
                    const float v = acc[rf][cb][j] + bv[cb];
                    C[(size_t)row * 128 + col] = v;
                    s[cb] += v;
                    q[cb] += v * v;
                }
            }
        }
    }
#pragma unroll
    for (int cb = 0; cb < 8; ++cb) {
        float ss = s[cb]; ss += __shfl_down(ss, 32); ss += __shfl_down(ss, 16);
        float qq = q[cb]; qq += __shfl_down(qq, 32); qq += __shfl_down(qq, 16);
        if (lane < 16) {
            atomicAdd(&bsum[cb * 16 + lane], ss);
            atomicAdd(&bsum[128 + cb * 16 + lane], qq);
        }
    }
    __syncthreads();
    unsafeAtomicAdd(&sums[tid], bsum[tid]);
}

// ---------------------------------------------------------------------------
__global__ __launch_bounds__(128) void bn_finalize_kernel(
    const float* __restrict__ sums,
    const float* __restrict__ gamma, const float* __restrict__ beta,
    float* __restrict__ scsh, float invM)
{
    const int c = threadIdx.x;
    const float mu  = sums[c] * invM;
    const float var = sums[128 + c] * invM - mu * mu;
    const float sc  = gamma[c] * rsqrtf(var + BN_EPS);
    scsh[c]       = sc;
    scsh[128 + c] = beta[c] - mu * sc;
}

__global__ __launch_bounds__(256) void bn_apply_final(
    float* __restrict__ h, const float* __restrict__ scsh, int M)
{
    __shared__ float sc[128], sh[128];
    if (threadIdx.x < 128) {
        sc[threadIdx.x] = scsh[threadIdx.x];
        sh[threadIdx.x] = scsh[128 + threadIdx.x];
    }
    __syncthreads();
    const size_t total = (size_t)M * D_DIM / 4;
    for (size_t i = (size_t)blockIdx.x * 256 + threadIdx.x; i < total;
         i += (size_t)gridDim.x * 256) {
        float4 v = ((const float4*)h)[i];
        const int cb = ((int)(i & 31)) * 4;
        v.x = fmaxf(fmaf(v.x, sc[cb + 0], sh[cb + 0]), 0.f);
        v.y = fmaxf(fmaf(v.y, sc[cb + 1], sh[cb + 1]), 0.f);
        v.z = fmaxf(fmaf(v.z, sc[cb + 2], sh[cb + 2]), 0.f);
        v.w = fmaxf(fmaf(v.w, sc[cb + 3], sh[cb + 3]), 0.f);
        ((float4*)h)[i] = v;
    }
}

// ---------------------------------------------------------------------------
extern "C" void kernel_launch(void* const* d_in, const int* in_sizes, int n_in,
                              void* d_out, int out_size, void* d_ws, size_t ws_size,
                              hipStream_t stream)
{
    const float* x_in  = (const float*)d_in[0];
    const int*   ei    = (const int*)  d_in[1];
    const float* ea    = (const float*)d_in[2];
    const float* W_lin = (const float*)d_in[3];
    const float* b_lin = (const float*)d_in[4];
    const float* W1    = (const float*)d_in[5];
    const float* b1    = (const float*)d_in[6];
    const float* W2    = (const float*)d_in[7];
    const float* b2    = (const float*)d_in[8];
    const float* gamma = (const float*)d_in[9];
    const float* beta  = (const float*)d_in[10];

    const int N = in_sizes[0] / D_DIM;              // 50000
    const int E = in_sizes[2] / EDGE_DIM;           // 600000
    const int L = in_sizes[3] / (EDGE_DIM * D_DIM); // 3

    const int* src = ei;
    const int* dst = ei + E;

    float* out = (float*)d_out;

    // ---- ws layout (16B-aligned regions) ----
    char* wp = (char*)d_ws;
    auto take = [&wp](size_t bytes) {
        char* r = wp;
        wp += (bytes + 15) & ~(size_t)15;
        return r;
    };
    float*     agg     = (float*)    take((size_t)N * D_DIM * 4);
    ushort_t*  h1      = (ushort_t*) take((size_t)N * D_DIM * 2);
    unsigned*  x16d    = (unsigned*) take((size_t)N * D_DIM * 2);
    float*     sums    = (float*)    take(256 * 4);
    float*     scsh    = (float*)    take(256 * 4);
    unsigned*  wl16d   = (unsigned*) take(16 * 128 * 4);
    int*       cnt     = (int*)      take((size_t)N * 4);
    int*       row_off = (int*)      take((size_t)(N + 1) * 4);
    int*       cur     = (int*)      take((size_t)N * 4);
    int*       blksum  = (int*)      take(256 * 4);
    int*       srcs    = (int*)      take((size_t)E * 4);
    int*       csr_eid = (int*)      take((size_t)E * 4);
    uint4*     ea16q   = (uint4*)    take((size_t)E * 64);

    const int gemmBlocks = (N + 127) / 128;
    const int scanBlocks = (N + 2047) / 2048;

    // ---- CSR build + edge_attr fp16 permute (once per call) ----
    hipMemsetAsync(cnt, 0, (size_t)N * sizeof(int), stream);
    hist_kernel<<<1024, 256, 0, stream>>>(dst, cnt, E);
    scan_local_kernel<<<scanBlocks, 256, 0, stream>>>(cnt, row_off, blksum, N);
    scan_tops_kernel<<<1, 64, 0, stream>>>(blksum, row_off, N, scanBlocks);
    scan_add_kernel<<<scanBlocks, 256, 0, stream>>>(row_off, cur, blksum, N);
    scatter_kernel<<<1024, 256, 0, stream>>>(src, dst, cur, srcs, csr_eid, E);
    ea_permute_kernel<<<(E * 4 + 255) / 256, 256, 0, stream>>>(ea, csr_eid, ea16q, E);

    for (int l = 0; l < L; ++l) {
        hipMemsetAsync(sums, 0, 256 * sizeof(float), stream);

        const float* Wl_l = W_lin + (size_t)l * EDGE_DIM * D_DIM;
        const float* bl_l = b_lin + (size_t)l * D_DIM;
        const float* W1_l = W1 + (size_t)l * D_DIM * D_DIM;
        const float* b1_l = b1 + (size_t)l * D_DIM;
        const float* W2_l = W2 + (size_t)l * D_DIM * D_DIM;
        const float* b2_l = b2 + (size_t)l * D_DIM;

        if (l == 0)
            xprep_kernel<0><<<2048, 256, 0, stream>>>(x_in, nullptr, (uint2*)x16d, N);
        else
            xprep_kernel<1><<<2048, 256, 0, stream>>>(out, scsh, (uint2*)x16d, N);

        wl_build_kernel<<<1, 256, 0, stream>>>(Wl_l, wl16d);

        edge_agg_kernel<<<2048, 256, 0, stream>>>(
            x16d, srcs, ea16q, row_off, wl16d, bl_l, agg, N);

        gemm1_kernel<<<gemmBlocks, 256, 0, stream>>>(
            x16d, agg, W1_l, b1_l, h1, N);

        gemm2_kernel<<<gemmBlocks, 256, 0, stream>>>(
            h1, W2_l, b2_l, out, sums, N);

        bn_finalize_kernel<<<1, 128, 0, stream>>>(
            sums, gamma + (size_t)l * D_DIM, beta + (size_t)l * D_DIM,
            scsh, 1.f / (float)N);
    }

    bn_apply_final<<<2048, 256, 0, stream>>>(out, scsh, N);
}

// Round 7
// 433.051 us; speedup vs baseline: 1.9811x; 1.1098x over previous
//
#include <hip/hip_runtime.h>

#define D_DIM 128
#define EDGE_DIM 32
#define BN_EPS 1e-5f

typedef __attribute__((ext_vector_type(8))) _Float16 f16x8;
typedef __attribute__((ext_vector_type(2))) _Float16 half2v;
typedef __attribute__((ext_vector_type(4))) float f32x4;
typedef unsigned short ushort_t;

__device__ __forceinline__ unsigned short f2h(float f) {
    union { _Float16 h; unsigned short u; } c;
    c.h = (_Float16)f;
    return c.u;
}
__device__ __forceinline__ unsigned pk2h(float lo, float hi) {
    return (unsigned)f2h(lo) | ((unsigned)f2h(hi) << 16);
}
__device__ __forceinline__ half2v asH2(unsigned u) {
    union { unsigned u; half2v h; } c;
    c.u = u;
    return c.h;
}
__device__ __forceinline__ float fdot2f(half2v a, half2v b, float c) {
#if __has_builtin(__builtin_amdgcn_fdot2)
    return __builtin_amdgcn_fdot2(a, b, c, false);
#else
    return c + (float)a.x * (float)b.x + (float)a.y * (float)b.y;
#endif
}

// ---------------------------------------------------------------------------
// CSR build: histogram -> multi-block scan -> scatter(+fp16 convert)
// ---------------------------------------------------------------------------
__global__ __launch_bounds__(256) void hist_kernel(
    const int* __restrict__ dst, int* __restrict__ cnt, int E)
{
    for (int e = blockIdx.x * 256 + threadIdx.x; e < E; e += gridDim.x * 256)
        atomicAdd(&cnt[dst[e]], 1);
}

__global__ __launch_bounds__(256) void scan_local_kernel(
    const int* __restrict__ cnt, int* __restrict__ off,
    int* __restrict__ blksum, int n)
{
    __shared__ int part[256];
    const int t = threadIdx.x;
    const int base = blockIdx.x * 2048 + t * 8;
    int v[8];
    int s = 0;
#pragma unroll
    for (int j = 0; j < 8; ++j) {
        const int idx = base + j;
        const int c = (idx < n) ? cnt[idx] : 0;
        v[j] = s;
        s += c;
    }
    part[t] = s;
    __syncthreads();
    for (int d = 1; d < 256; d <<= 1) {
        const int val = (t >= d) ? part[t - d] : 0;
        __syncthreads();
        part[t] += val;
        __syncthreads();
    }
    const int texcl = (t > 0) ? part[t - 1] : 0;
#pragma unroll
    for (int j = 0; j < 8; ++j) {
        const int idx = base + j;
        if (idx < n) off[idx] = texcl + v[j];
    }
    if (t == 255) blksum[blockIdx.x] = part[255];
}

__global__ __launch_bounds__(64) void scan_tops_kernel(
    int* __restrict__ blksum, int* __restrict__ off, int n, int B)
{
    if (threadIdx.x == 0) {
        int run = 0;
        for (int b = 0; b < B; ++b) {
            const int v = blksum[b];
            blksum[b] = run;
            run += v;
        }
        off[n] = run;
    }
}

__global__ __launch_bounds__(256) void scan_add_kernel(
    int* __restrict__ off, int* __restrict__ cur,
    const int* __restrict__ blksum, int n)
{
    const int base = blockIdx.x * 2048;
    const int add = blksum[blockIdx.x];
    for (int j = threadIdx.x; j < 2048; j += 256) {
        const int i = base + j;
        if (i < n) {
            const int v = off[i] + add;
            off[i] = v;
            cur[i] = v;
        }
    }
}

// scatter + inline edge_attr fp16 conversion into CSR order
__global__ __launch_bounds__(256) void scatter_conv_kernel(
    const int* __restrict__ src, const int* __restrict__ dst,
    const float* __restrict__ ea,
    int* __restrict__ cur, int* __restrict__ srcs,
    uint4* __restrict__ ea16q, int E)
{
    for (int e = blockIdx.x * 256 + threadIdx.x; e < E; e += gridDim.x * 256) {
        const int p = atomicAdd(&cur[dst[e]], 1);
        srcs[p] = src[e];
        const float* __restrict__ er = ea + (size_t)e * EDGE_DIM;
#pragma unroll
        for (int q = 0; q < 4; ++q) {
            const float4 a = *(const float4*)(er + q * 8);
            const float4 b = *(const float4*)(er + q * 8 + 4);
            uint4 o;
            o.x = pk2h(a.x, a.y); o.y = pk2h(a.z, a.w);
            o.z = pk2h(b.x, b.y); o.w = pk2h(b.z, b.w);
            ea16q[(size_t)p * 4 + q] = o;
        }
    }
}

// ---------------------------------------------------------------------------
// W_lin (32x128 fp32) -> k-pair-packed fp16
// ---------------------------------------------------------------------------
__global__ __launch_bounds__(256) void wl_build_kernel(
    const float* __restrict__ Wl, unsigned* __restrict__ wl16d)
{
#pragma unroll
    for (int r = 0; r < 8; ++r) {
        const int idx = r * 256 + threadIdx.x;
        const int kp = idx >> 7, c = idx & 127;
        wl16d[idx] = pk2h(Wl[(2 * kp) * D_DIM + c], Wl[(2 * kp + 1) * D_DIM + c]);
    }
}

// ---------------------------------------------------------------------------
// xprep0: fp32 x -> fp16 x16 (layer 0 only)
// ---------------------------------------------------------------------------
__global__ __launch_bounds__(256) void xprep0_kernel(
    const float* __restrict__ h, uint2* __restrict__ x16q, int M)
{
    const int total = M * 32;
    for (int i = blockIdx.x * 256 + threadIdx.x; i < total; i += gridDim.x * 256) {
        const float4 v = ((const float4*)h)[i];
        uint2 o; o.x = pk2h(v.x, v.y); o.y = pk2h(v.z, v.w);
        x16q[i] = o;
    }
}

// ---------------------------------------------------------------------------
// apply: x = relu(h16*sc + sh); emit fp16 x16 (OUTF32=0) or fp32 out (=1)
// ---------------------------------------------------------------------------
template<int OUTF32>
__global__ __launch_bounds__(256) void apply_kernel(
    const ushort_t* __restrict__ h16, const float* __restrict__ scsh,
    uint2* __restrict__ x16q, float* __restrict__ outp, int M)
{
    __shared__ float sc[128], sh[128];
    if (threadIdx.x < 128) {
        sc[threadIdx.x] = scsh[threadIdx.x];
        sh[threadIdx.x] = scsh[128 + threadIdx.x];
    }
    __syncthreads();
    const int total = M * 32;
    for (int i = blockIdx.x * 256 + threadIdx.x; i < total; i += gridDim.x * 256) {
        const uint2 hv = *(const uint2*)(h16 + (size_t)i * 4);
        const half2v a = asH2(hv.x), b = asH2(hv.y);
        const int c = (i & 31) * 4;
        const float v0 = fmaxf(fmaf((float)a.x, sc[c + 0], sh[c + 0]), 0.f);
        const float v1 = fmaxf(fmaf((float)a.y, sc[c + 1], sh[c + 1]), 0.f);
        const float v2 = fmaxf(fmaf((float)b.x, sc[c + 2], sh[c + 2]), 0.f);
        const float v3 = fmaxf(fmaf((float)b.y, sc[c + 3], sh[c + 3]), 0.f);
        if (OUTF32) {
            f32x4 o = {v0, v1, v2, v3};
            *(f32x4*)(outp + (size_t)i * 4) = o;
        } else {
            uint2 o; o.x = pk2h(v0, v1); o.y = pk2h(v2, v3);
            x16q[i] = o;
        }
    }
}

// ---------------------------------------------------------------------------
// Edge aggregation: one wave per node, fp16 gather + fdot2 matvec, 4-edge ILP.
// ---------------------------------------------------------------------------
__global__ __launch_bounds__(256) void edge_agg_kernel(
    const unsigned* __restrict__ x16d,
    const int*      __restrict__ srcs,
    const uint4*    __restrict__ ea16q,
    const int*      __restrict__ row_off,
    const unsigned* __restrict__ wl16d,
    const float*    __restrict__ bl,
    float*          __restrict__ agg,
    int nNodes)
{
    const int lane = threadIdx.x & 63;
    const int wid  = threadIdx.x >> 6;

    unsigned wA[16], wB[16];
#pragma unroll
    for (int kp = 0; kp < 16; ++kp) {
        const uint2 w2 = *(const uint2*)(wl16d + kp * 128 + 2 * lane);
        wA[kp] = w2.x; wB[kp] = w2.y;
    }
    const float b0 = bl[2 * lane];
    const float b1 = bl[2 * lane + 1];

    const int stride = gridDim.x * 4;
    for (int node = blockIdx.x * 4 + wid; node < nNodes; node += stride) {
        const int beg = __builtin_amdgcn_readfirstlane(row_off[node]);
        const int end = __builtin_amdgcn_readfirstlane(row_off[node + 1]);
        float acc0 = 0.f, acc1 = 0.f;

        auto edge_body = [&](int p) {
            const int s = srcs[p];
            const uint4 q0 = ea16q[(size_t)p * 4 + 0];
            const uint4 q1 = ea16q[(size_t)p * 4 + 1];
            const uint4 q2 = ea16q[(size_t)p * 4 + 2];
            const uint4 q3 = ea16q[(size_t)p * 4 + 3];
            const unsigned xd = x16d[(size_t)s * 64 + lane];
            const unsigned aw[16] = {q0.x, q0.y, q0.z, q0.w,
                                     q1.x, q1.y, q1.z, q1.w,
                                     q2.x, q2.y, q2.z, q2.w,
                                     q3.x, q3.y, q3.z, q3.w};
            float e0 = b0, e1 = b1;
#pragma unroll
            for (int kp = 0; kp < 16; ++kp) {
                e0 = fdot2f(asH2(aw[kp]), asH2(wA[kp]), e0);
                e1 = fdot2f(asH2(aw[kp]), asH2(wB[kp]), e1);
            }
            const half2v xh = asH2(xd);
            acc0 += fmaxf((float)xh.x + e0, 0.f);
            acc1 += fmaxf((float)xh.y + e1, 0.f);
        };

        int j = beg;
        const int head = (end - beg) & 3;
#pragma unroll 1
        for (int t = 0; t < head; ++t) { edge_body(j); ++j; }
#pragma unroll 1
        for (; j < end; j += 4) {
            edge_body(j);
            edge_body(j + 1);
            edge_body(j + 2);
            edge_body(j + 3);
        }
        *(float2*)(agg + (size_t)node * D_DIM + 2 * lane) = make_float2(acc0, acc1);
    }
}

// ---------------------------------------------------------------------------
// Fused MLP: h16 = (relu((x16+agg)@W1+b1)) @ W2 + b2, fp16 out (pre-BN),
// + fused BN column sums/sumsq. h1 tile never leaves LDS.
// ---------------------------------------------------------------------------
__global__ __launch_bounds__(256) void fused_mlp_kernel(
    const unsigned* __restrict__ x16d,
    const float* __restrict__ agg,
    const float* __restrict__ W1,
    const float* __restrict__ b1,
    const float* __restrict__ W2,
    const float* __restrict__ b2,
    ushort_t* __restrict__ h16,
    float* __restrict__ sums,
    int M)
{
    __shared__ char ATb[128 * 256];
    __shared__ char WTb[128 * 256];
    __shared__ float bsum[256];
    const int tid = threadIdx.x;
    const int m0  = blockIdx.x * 128;

    bsum[tid] = 0.f;

    // --- stage A = x16 + agg (fp16) ---
#pragma unroll
    for (int i = 0; i < 16; ++i) {
        const int idx = i * 256 + tid;
        const int r = idx >> 5, c4 = idx & 31;
        const int row = m0 + r;
        f32x4 v = {0.f, 0.f, 0.f, 0.f};
        if (row < M) {
            const uint2 xv = *(const uint2*)(x16d + (size_t)row * 64 + c4 * 2);
            const f32x4 g  = *(const f32x4*)(agg + (size_t)row * 128 + c4 * 4);
            const half2v xa = asH2(xv.x), xb = asH2(xv.y);
            v[0] = (float)xa.x + g[0];
            v[1] = (float)xa.y + g[1];
            v[2] = (float)xb.x + g[2];
            v[3] = (float)xb.y + g[3];
        }
        uint2 p; p.x = pk2h(v[0], v[1]); p.y = pk2h(v[2], v[3]);
        *(uint2*)(ATb + r * 256 + ((c4 * 8) ^ ((r & 7) << 4))) = p;
    }
    // --- stage W1 ---
#pragma unroll
    for (int i = 0; i < 8; ++i) {
        const int c4 = (tid >> 6) + 4 * i;
        const int kp = tid & 63;
        const f32x4 wa = *(const f32x4*)(W1 + (size_t)(2 * kp) * 128 + c4 * 4);
        const f32x4 wb = *(const f32x4*)(W1 + (size_t)(2 * kp + 1) * 128 + c4 * 4);
#pragma unroll
        for (int j = 0; j < 4; ++j) {
            const int col = c4 * 4 + j;
            *(unsigned*)(WTb + col * 256 + ((kp * 4) ^ ((col & 7) << 4))) = pk2h(wa[j], wb[j]);
        }
    }
    __syncthreads();

    const int lane = tid & 63;
    const int w    = tid >> 6;
    const int fr   = lane & 15;
    const int fg   = lane >> 4;
    const int ar0  = w * 32 + fr;
    const int asz  = (ar0 & 7) << 4;

    f32x4 acc[2][8];
#pragma unroll
    for (int a = 0; a < 2; ++a)
#pragma unroll
        for (int b = 0; b < 8; ++b) acc[a][b] = (f32x4){0.f, 0.f, 0.f, 0.f};

    // --- MFMA 1 ---
#pragma unroll
    for (int ks = 0; ks < 4; ++ks) {
        const int kb = ks * 64 + fg * 16;
        const f16x8 a0 = *(const f16x8*)(ATb + ar0 * 256 + (kb ^ asz));
        const f16x8 a1 = *(const f16x8*)(ATb + (ar0 + 16) * 256 + (kb ^ asz));
#pragma unroll
        for (int cb = 0; cb < 8; ++cb) {
            const int col = cb * 16 + fr;
            const f16x8 b = *(const f16x8*)(WTb + col * 256 + (kb ^ ((col & 7) << 4)));
            acc[0][cb] = __builtin_amdgcn_mfma_f32_16x16x32_f16(a0, b, acc[0][cb], 0, 0, 0);
            acc[1][cb] = __builtin_amdgcn_mfma_f32_16x16x32_f16(a1, b, acc[1][cb], 0, 0, 0);
        }
    }
    __syncthreads();   // all MFMA1 LDS reads done before overwrite

    // --- write relu(h1) tile back into ATb (fp16, same swizzled layout) ---
    {
        float b1v[8];
#pragma unroll
        for (int cb = 0; cb < 8; ++cb) b1v[cb] = b1[cb * 16 + fr];
#pragma unroll
        for (int rf = 0; rf < 2; ++rf) {
            const int rb = w * 32 + rf * 16 + fg * 4;
#pragma unroll
            for (int cb = 0; cb < 8; ++cb) {
                const int c = cb * 16 + fr;
#pragma unroll
                for (int j = 0; j < 4; ++j) {
                    const int r = rb + j;
                    const float v = fmaxf(acc[rf][cb][j] + b1v[cb], 0.f);
                    *(ushort_t*)(ATb + r * 256 + ((c * 2) ^ ((r & 7) << 4))) = f2h(v);
                }
            }
        }
    }
    // --- stage W2 ---
#pragma unroll
    for (int i = 0; i < 8; ++i) {
        const int c4 = (tid >> 6) + 4 * i;
        const int kp = tid & 63;
        const f32x4 wa = *(const f32x4*)(W2 + (size_t)(2 * kp) * 128 + c4 * 4);
        const f32x4 wb = *(const f32x4*)(W2 + (size_t)(2 * kp + 1) * 128 + c4 * 4);
#pragma unroll
        for (int j = 0; j < 4; ++j) {
            const int col = c4 * 4 + j;
            *(unsigned*)(WTb + col * 256 + ((kp * 4) ^ ((col & 7) << 4))) = pk2h(wa[j], wb[j]);
        }
    }
#pragma unroll
    for (int a = 0; a < 2; ++a)
#pragma unroll
        for (int b = 0; b < 8; ++b) acc[a][b] = (f32x4){0.f, 0.f, 0.f, 0.f};
    __syncthreads();

    // --- MFMA 2 ---
#pragma unroll
    for (int ks = 0; ks < 4; ++ks) {
        const int kb = ks * 64 + fg * 16;
        const f16x8 a0 = *(const f16x8*)(ATb + ar0 * 256 + (kb ^ asz));
        const f16x8 a1 = *(const f16x8*)(ATb + (ar0 + 16) * 256 + (kb ^ asz));
#pragma unroll
        for (int cb = 0; cb < 8; ++cb) {
            const int col = cb * 16 + fr;
            const f16x8 b = *(const f16x8*)(WTb + col * 256 + (kb ^ ((col & 7) << 4)));
            acc[0][cb] = __builtin_amdgcn_mfma_f32_16x16x32_f16(a0, b, acc[0][cb], 0, 0, 0);
            acc[1][cb] = __builtin_amdgcn_mfma_f32_16x16x32_f16(a1, b, acc[1][cb], 0, 0, 0);
        }
    }

    // --- epilogue: bias, BN sums, fp16 h out ---
    float b2v[8];
#pragma unroll
    for (int cb = 0; cb < 8; ++cb) b2v[cb] = b2[cb * 16 + fr];
    float s[8], q[8];
#pragma unroll
    for (int cb = 0; cb < 8; ++cb) { s[cb] = 0.f; q[cb] = 0.f; }

#pragma unroll
    for (int rf = 0; rf < 2; ++rf) {
        const int r0 = m0 + w * 32 + rf * 16 + fg * 4;
#pragma unroll
        for (int cb = 0; cb < 8; ++cb) {
            const int col = cb * 16 + fr;
#pragma unroll
            for (int j = 0; j < 4; ++j) {
                const int row = r0 + j;
                if (row < M) {
                    const float v = acc[rf][cb][j] + b2v[cb];
                    h16[(size_t)row * 128 + col] = f2h(v);
                    s[cb] += v;
                    q[cb] += v * v;
                }
            }
        }
    }
#pragma unroll
    for (int cb = 0; cb < 8; ++cb) {
        float ss = s[cb]; ss += __shfl_down(ss, 32); ss += __shfl_down(ss, 16);
        float qq = q[cb]; qq += __shfl_down(qq, 32); qq += __shfl_down(qq, 16);
        if (lane < 16) {
            atomicAdd(&bsum[cb * 16 + lane], ss);
            atomicAdd(&bsum[128 + cb * 16 + lane], qq);
        }
    }
    __syncthreads();
    unsafeAtomicAdd(&sums[tid], bsum[tid]);
}

// ---------------------------------------------------------------------------
__global__ __launch_bounds__(128) void bn_finalize_kernel(
    const float* __restrict__ sums,
    const float* __restrict__ gamma, const float* __restrict__ beta,
    float* __restrict__ scsh, float invM)
{
    const int c = threadIdx.x;
    const float mu  = sums[c] * invM;
    const float var = sums[128 + c] * invM - mu * mu;
    const float sc  = gamma[c] * rsqrtf(var + BN_EPS);
    scsh[c]       = sc;
    scsh[128 + c] = beta[c] - mu * sc;
}

// ---------------------------------------------------------------------------
extern "C" void kernel_launch(void* const* d_in, const int* in_sizes, int n_in,
                              void* d_out, int out_size, void* d_ws, size_t ws_size,
                              hipStream_t stream)
{
    const float* x_in  = (const float*)d_in[0];
    const int*   ei    = (const int*)  d_in[1];
    const float* ea    = (const float*)d_in[2];
    const float* W_lin = (const float*)d_in[3];
    const float* b_lin = (const float*)d_in[4];
    const float* W1    = (const float*)d_in[5];
    const float* b1    = (const float*)d_in[6];
    const float* W2    = (const float*)d_in[7];
    const float* b2    = (const float*)d_in[8];
    const float* gamma = (const float*)d_in[9];
    const float* beta  = (const float*)d_in[10];

    const int N = in_sizes[0] / D_DIM;              // 50000
    const int E = in_sizes[2] / EDGE_DIM;           // 600000
    const int L = in_sizes[3] / (EDGE_DIM * D_DIM); // 3

    const int* src = ei;
    const int* dst = ei + E;

    float* out = (float*)d_out;

    // ---- ws layout (16B-aligned regions) ----
    char* wp = (char*)d_ws;
    auto take = [&wp](size_t bytes) {
        char* r = wp;
        wp += (bytes + 15) & ~(size_t)15;
        return r;
    };
    float*     agg     = (float*)    take((size_t)N * D_DIM * 4);
    ushort_t*  h16     = (ushort_t*) take((size_t)N * D_DIM * 2);
    unsigned*  x16d    = (unsigned*) take((size_t)N * D_DIM * 2);
    float*     sums    = (float*)    take(256 * 4);
    float*     scsh    = (float*)    take(256 * 4);
    unsigned*  wl16d   = (unsigned*) take(16 * 128 * 4);
    int*       cnt     = (int*)      take((size_t)N * 4);
    int*       row_off = (int*)      take((size_t)(N + 1) * 4);
    int*       cur     = (int*)      take((size_t)N * 4);
    int*       blksum  = (int*)      take(256 * 4);
    int*       srcs    = (int*)      take((size_t)E * 4);
    uint4*     ea16q   = (uint4*)    take((size_t)E * 64);

    const int gemmBlocks = (N + 127) / 128;
    const int scanBlocks = (N + 2047) / 2048;

    // ---- CSR build + fp16 edge_attr (once per call) ----
    hipMemsetAsync(cnt, 0, (size_t)N * sizeof(int), stream);
    hist_kernel<<<1024, 256, 0, stream>>>(dst, cnt, E);
    scan_local_kernel<<<scanBlocks, 256, 0, stream>>>(cnt, row_off, blksum, N);
    scan_tops_kernel<<<1, 64, 0, stream>>>(blksum, row_off, N, scanBlocks);
    scan_add_kernel<<<scanBlocks, 256, 0, stream>>>(row_off, cur, blksum, N);
    scatter_conv_kernel<<<1024, 256, 0, stream>>>(src, dst, ea, cur, srcs, ea16q, E);

    for (int l = 0; l < L; ++l) {
        hipMemsetAsync(sums, 0, 256 * sizeof(float), stream);

        const float* Wl_l = W_lin + (size_t)l * EDGE_DIM * D_DIM;
        const float* bl_l = b_lin + (size_t)l * D_DIM;
        const float* W1_l = W1 + (size_t)l * D_DIM * D_DIM;
        const float* b1_l = b1 + (size_t)l * D_DIM;
        const float* W2_l = W2 + (size_t)l * D_DIM * D_DIM;
        const float* b2_l = b2 + (size_t)l * D_DIM;

        if (l == 0)
            xprep0_kernel<<<1024, 256, 0, stream>>>(x_in, (uint2*)x16d, N);
        else
            apply_kernel<0><<<1024, 256, 0, stream>>>(h16, scsh, (uint2*)x16d, nullptr, N);

        wl_build_kernel<<<1, 256, 0, stream>>>(Wl_l, wl16d);

        edge_agg_kernel<<<2048, 256, 0, stream>>>(
            x16d, srcs, ea16q, row_off, wl16d, bl_l, agg, N);

        fused_mlp_kernel<<<gemmBlocks, 256, 0, stream>>>(
            x16d, agg, W1_l, b1_l, W2_l, b2_l, h16, sums, N);

        bn_finalize_kernel<<<1, 128, 0, stream>>>(
            sums, gamma + (size_t)l * D_DIM, beta + (size_t)l * D_DIM,
            scsh, 1.f / (float)N);
    }

    apply_kernel<1><<<1024, 256, 0, stream>>>(h16, scsh, nullptr, out, N);
}